// Round 6
// baseline (613.993 us; speedup 1.0000x reference)
//
#include <hip/hip_runtime.h>

#define NF 128
#define NR 6

// ---------------------------------------------------------------------------
// Pass 1: histogram of atom indices.
// ---------------------------------------------------------------------------
__global__ __launch_bounds__(256) void hist_kernel(
    const int* __restrict__ idx, int* __restrict__ count, int E)
{
    int stride = gridDim.x * blockDim.x;
    for (int e = blockIdx.x * blockDim.x + threadIdx.x; e < E; e += stride)
        atomicAdd(&count[idx[e]], 1);
}

// ---------------------------------------------------------------------------
// Pass 2: exclusive scan, one dispatch, 256 blocks (redundant prefix).
// ---------------------------------------------------------------------------
#define SCAN_BLOCKS 256

__global__ __launch_bounds__(256) void scan_all_kernel(
    const int* __restrict__ count, int* __restrict__ offsets,
    int* __restrict__ cursor, int N)
{
    __shared__ int red[256];
    __shared__ int tile[256];
    const int b = blockIdx.x, t = threadIdx.x;
    const int chunk = (N + SCAN_BLOCKS - 1) / SCAN_BLOCKS;
    const int lo = b * chunk;
    const int hi = min(lo + chunk, N);

    int s = 0;
    for (int i = t; i < lo; i += 256) s += count[i];
    red[t] = s;
    __syncthreads();
    for (int d = 128; d > 0; d >>= 1) {
        if (t < d) red[t] += red[t + d];
        __syncthreads();
    }
    int base = red[0];

    for (int p = lo; p < hi; p += 256) {
        int v = (p + t < hi) ? count[p + t] : 0;
        tile[t] = v;
        __syncthreads();
        for (int d = 1; d < 256; d <<= 1) {
            int u = (t >= d) ? tile[t - d] : 0;
            __syncthreads();
            tile[t] += u;
            __syncthreads();
        }
        if (p + t < hi) {
            int excl = base + tile[t] - v;
            offsets[p + t] = excl;
            cursor[p + t]  = excl;
            if (p + t == N - 1) offsets[N] = excl + v;
        }
        base += tile[255];
        __syncthreads();
    }
}

// ---------------------------------------------------------------------------
// Pass 3: reorder edge ids + rbf payload into segment order.
// ---------------------------------------------------------------------------
__global__ __launch_bounds__(256) void reorder_kernel(
    const int* __restrict__ idx, const float* __restrict__ rbf,
    int* __restrict__ cursor, int* __restrict__ sorted,
    float* __restrict__ srbf, int E)
{
    long stride = (long)gridDim.x * blockDim.x;
    for (long e = blockIdx.x * blockDim.x + threadIdx.x; e < E; e += stride) {
        int a = idx[e];
        int pos = atomicAdd(&cursor[a], 1);
        sorted[pos] = (int)e;
        const float2* rp = (const float2*)(rbf + e * NR);
        float2 r0 = rp[0], r1 = rp[1], r2 = rp[2];
        float2* dp = (float2*)(srbf + (long)pos * NR);
        dp[0] = r0; dp[1] = r1; dp[2] = r2;
    }
}

// ---------------------------------------------------------------------------
// Pass 4: fused gather + rbf projection + per-atom MLP (R3 structure, deeper
// pipeline). Block = 256 = 4 waves, 16 atoms/block. Each wave: 2 atoms in
// PARALLEL (32-lane halves) x 2 sequential. Half-lane hl owns features
// 4*hl..4*hl+3; one float4 load covers a full 512B edge row per half.
// Batches of 8 edges, register double-buffered m prefetch (8KB in flight per
// wave). rbf (srbf, position-sequential) loads issued oldest-first each
// iteration so compute waits only on them, not the prefetch.
// ---------------------------------------------------------------------------
__global__ __launch_bounds__(256) void gather_mlp_kernel(
    const float* __restrict__ m, const int* __restrict__ offsets,
    const int* __restrict__ sorted, const float* __restrict__ srbf,
    const float* __restrict__ W_rbf, const float* __restrict__ W1,
    const float* __restrict__ b1, const float* __restrict__ W2,
    const float* __restrict__ b2, float* __restrict__ out, int N)
{
    __shared__ float W1t[128][68];   // 34.8 KB transposed W1 (padded)
    __shared__ float sb[4][4][132];  // 8.4 KB swish-ed atom features

    const int t = threadIdx.x;
    const int lane = t & 63;
    const int w = t >> 6;
    const int h  = lane >> 5;   // half-wave 0/1
    const int hl = lane & 31;   // lane within half

    // stage W1 transposed (vectorized); only consumer is the MLP tail
    for (int k4 = t; k4 < 64 * 128 / 4; k4 += 256) {
        int k = k4 * 4;
        int j = k >> 7, f = k & 127;
        float4 v = *(const float4*)(W1 + k);
        W1t[f + 0][j] = v.x; W1t[f + 1][j] = v.y;
        W1t[f + 2][j] = v.z; W1t[f + 3][j] = v.w;
    }

    // per-lane W_rbf rows for features 4*hl..4*hl+3
    float wr[4][NR];
#pragma unroll
    for (int c = 0; c < 4; ++c)
#pragma unroll
        for (int r = 0; r < NR; ++r)
            wr[c][r] = W_rbf[(4 * hl + c) * NR + r];

    __syncthreads();   // W1t ready (gather below doesn't touch it)

    const int nb = blockIdx.x * 16 + w * 4;

    for (int ta = 0; ta < 2; ++ta) {
        const int n = nb + ta * 2 + h;
        float a0 = 0.f, a1 = 0.f, a2 = 0.f, a3 = 0.f;
        int beg = 0, end = 0;
        if (n < N) { beg = offsets[n]; end = offsets[n + 1]; }

        // 32-deep per-half register cache of edge ids
        int eid = (beg + hl < end) ? sorted[beg + hl] : 0;

        float4 mv_cur[8], mv_nxt[8];
        int e_cur[8], e_nxt[8];

        // prologue: batch 0
        {
            const int cnt0 = min(end - beg, 8);
#pragma unroll
            for (int k = 0; k < 8; ++k) {
                e_cur[k] = __shfl(eid, (h << 5) + ((k < cnt0) ? k : 0));
                mv_cur[k] = *(const float4*)(m + (long)e_cur[k] * NF + hl * 4);
            }
        }

        for (int p = beg; p < end; p += 8) {
            const int cnt = min(end - p, 8);

            // rbf rows for CURRENT batch — issued first (oldest): compute's
            // vmcnt wait covers these without draining the newer prefetch.
            float2 rv[8][3];
#pragma unroll
            for (int k = 0; k < 8; ++k) {
                long pe = p + ((k < cnt) ? k : 0);
                const float2* rp = (const float2*)(srbf + pe * NR);
                rv[k][0] = rp[0]; rv[k][1] = rp[1]; rv[k][2] = rp[2];
            }

            // prefetch next batch of m rows
            const int pn = p + 8;
            if (pn < end) {
                const int cn = min(end - pn, 8);
#pragma unroll
                for (int k = 0; k < 8; ++k) {
                    int off = (pn - beg) + ((k < cn) ? k : 0);
                    int e;
                    if (off < 32) {
                        e = __shfl(eid, (h << 5) + off);
                    } else {
                        int q = pn + ((k < cn) ? k : 0);
                        e = (q < end) ? sorted[q] : __shfl(eid, h << 5);
                    }
                    e_nxt[k] = e;
                    mv_nxt[k] = *(const float4*)(m + (long)e * NF + hl * 4);
                }
            }

            // compute current batch
#pragma unroll
            for (int k = 0; k < 8; ++k) {
                if (k < cnt) {
                    float q0 = rv[k][0].x, q1 = rv[k][0].y;
                    float q2 = rv[k][1].x, q3 = rv[k][1].y;
                    float q4 = rv[k][2].x, q5 = rv[k][2].y;
                    float f0 = q0 * wr[0][0], f1 = q0 * wr[1][0];
                    float f2 = q0 * wr[2][0], f3 = q0 * wr[3][0];
                    f0 = fmaf(q1, wr[0][1], f0); f1 = fmaf(q1, wr[1][1], f1);
                    f2 = fmaf(q1, wr[2][1], f2); f3 = fmaf(q1, wr[3][1], f3);
                    f0 = fmaf(q2, wr[0][2], f0); f1 = fmaf(q2, wr[1][2], f1);
                    f2 = fmaf(q2, wr[2][2], f2); f3 = fmaf(q2, wr[3][2], f3);
                    f0 = fmaf(q3, wr[0][3], f0); f1 = fmaf(q3, wr[1][3], f1);
                    f2 = fmaf(q3, wr[2][3], f2); f3 = fmaf(q3, wr[3][3], f3);
                    f0 = fmaf(q4, wr[0][4], f0); f1 = fmaf(q4, wr[1][4], f1);
                    f2 = fmaf(q4, wr[2][4], f2); f3 = fmaf(q4, wr[3][4], f3);
                    f0 = fmaf(q5, wr[0][5], f0); f1 = fmaf(q5, wr[1][5], f1);
                    f2 = fmaf(q5, wr[2][5], f2); f3 = fmaf(q5, wr[3][5], f3);
                    a0 = fmaf(mv_cur[k].x, f0, a0);
                    a1 = fmaf(mv_cur[k].y, f1, a1);
                    a2 = fmaf(mv_cur[k].z, f2, a2);
                    a3 = fmaf(mv_cur[k].w, f3, a3);
                }
            }
#pragma unroll
            for (int k = 0; k < 8; ++k) { mv_cur[k] = mv_nxt[k]; e_cur[k] = e_nxt[k]; }
        }

        float s0 = a0 / (1.f + __expf(-a0));
        float s1 = a1 / (1.f + __expf(-a1));
        float s2 = a2 / (1.f + __expf(-a2));
        float s3 = a3 / (1.f + __expf(-a3));
        *(float4*)&sb[w][ta * 2 + h][4 * hl] = make_float4(s0, s1, s2, s3);
    }

    // NO block sync needed: sb[w] is written and read by wave w only.

    // layer 1: 16-lane group ag = atom (0..3 of this wave), lane lj owns
    // outputs 4*lj..4*lj+3
    const int ag = lane >> 4;
    const int lj = lane & 15;

    float4 bv = *(const float4*)(b1 + 4 * lj);
    float h0 = bv.x, h1 = bv.y, h2 = bv.z, h3 = bv.w;

    for (int f = 0; f < 128; f += 4) {
        float4 sv = *(const float4*)&sb[w][ag][f];
        float4 w0 = *(const float4*)&W1t[f + 0][4 * lj];
        float4 w1v = *(const float4*)&W1t[f + 1][4 * lj];
        float4 w2v = *(const float4*)&W1t[f + 2][4 * lj];
        float4 w3v = *(const float4*)&W1t[f + 3][4 * lj];
        h0 = fmaf(sv.x, w0.x, h0);  h1 = fmaf(sv.x, w0.y, h1);
        h2 = fmaf(sv.x, w0.z, h2);  h3 = fmaf(sv.x, w0.w, h3);
        h0 = fmaf(sv.y, w1v.x, h0); h1 = fmaf(sv.y, w1v.y, h1);
        h2 = fmaf(sv.y, w1v.z, h2); h3 = fmaf(sv.y, w1v.w, h3);
        h0 = fmaf(sv.z, w2v.x, h0); h1 = fmaf(sv.z, w2v.y, h1);
        h2 = fmaf(sv.z, w2v.z, h2); h3 = fmaf(sv.z, w2v.w, h3);
        h0 = fmaf(sv.w, w3v.x, h0); h1 = fmaf(sv.w, w3v.y, h1);
        h2 = fmaf(sv.w, w3v.z, h2); h3 = fmaf(sv.w, w3v.w, h3);
    }

    float4 w2 = *(const float4*)(W2 + 4 * lj);
    float r = (h0 / (1.f + __expf(-h0))) * w2.x
            + (h1 / (1.f + __expf(-h1))) * w2.y
            + (h2 / (1.f + __expf(-h2))) * w2.z
            + (h3 / (1.f + __expf(-h3))) * w2.w;

    r += __shfl_xor(r, 1);
    r += __shfl_xor(r, 2);
    r += __shfl_xor(r, 4);
    r += __shfl_xor(r, 8);

    int n = nb + ag;
    if (lj == 0 && n < N) out[n] = r + b2[0];
}

extern "C" void kernel_launch(void* const* d_in, const int* in_sizes, int n_in,
                              void* d_out, int out_size, void* d_ws, size_t ws_size,
                              hipStream_t stream) {
    const float* m     = (const float*)d_in[0];
    const float* rbf   = (const float*)d_in[1];
    const int*   idx   = (const int*)d_in[2];
    const float* W_rbf = (const float*)d_in[4];
    const float* W1    = (const float*)d_in[5];
    const float* b1    = (const float*)d_in[6];
    const float* W2    = (const float*)d_in[7];
    const float* b2    = (const float*)d_in[8];
    float* out = (float*)d_out;

    const int E = in_sizes[2];   // one atom index per edge
    const int N = out_size;      // out is [N, 1]

    // workspace layout (all segment starts 8B-aligned)
    int* count   = (int*)d_ws;                         // N
    int* offsets = count + N;                          // N+1
    int* cursor  = offsets + ((N + 2) & ~1);           // N
    int* sorted  = cursor + N;                         // E
    float* srbf  = (float*)(sorted + ((E + 1) & ~1));  // 6E floats

    hipMemsetAsync(count, 0, (size_t)N * sizeof(int), stream);

    hist_kernel<<<2048, 256, 0, stream>>>(idx, count, E);
    scan_all_kernel<<<SCAN_BLOCKS, 256, 0, stream>>>(count, offsets, cursor, N);
    reorder_kernel<<<2048, 256, 0, stream>>>(idx, rbf, cursor, sorted, srbf, E);
    gather_mlp_kernel<<<(N + 15) / 16, 256, 0, stream>>>(
        m, offsets, sorted, srbf, W_rbf, W1, b1, W2, b2, out, N);
}

// Round 7
// 493.785 us; speedup vs baseline: 1.2434x; 1.2434x over previous
//
#include <hip/hip_runtime.h>

#define NF 128
#define NR 6

// ---------------------------------------------------------------------------
// Pass 1: histogram of atom indices.
// ---------------------------------------------------------------------------
__global__ __launch_bounds__(256) void hist_kernel(
    const int* __restrict__ idx, int* __restrict__ count, int E)
{
    int stride = gridDim.x * blockDim.x;
    for (int e = blockIdx.x * blockDim.x + threadIdx.x; e < E; e += stride)
        atomicAdd(&count[idx[e]], 1);
}

// ---------------------------------------------------------------------------
// Pass 2: exclusive scan, one dispatch, 256 blocks (redundant prefix).
// ---------------------------------------------------------------------------
#define SCAN_BLOCKS 256

__global__ __launch_bounds__(256) void scan_all_kernel(
    const int* __restrict__ count, int* __restrict__ offsets,
    int* __restrict__ cursor, int N)
{
    __shared__ int red[256];
    __shared__ int tile[256];
    const int b = blockIdx.x, t = threadIdx.x;
    const int chunk = (N + SCAN_BLOCKS - 1) / SCAN_BLOCKS;
    const int lo = b * chunk;
    const int hi = min(lo + chunk, N);

    int s = 0;
    for (int i = t; i < lo; i += 256) s += count[i];
    red[t] = s;
    __syncthreads();
    for (int d = 128; d > 0; d >>= 1) {
        if (t < d) red[t] += red[t + d];
        __syncthreads();
    }
    int base = red[0];

    for (int p = lo; p < hi; p += 256) {
        int v = (p + t < hi) ? count[p + t] : 0;
        tile[t] = v;
        __syncthreads();
        for (int d = 1; d < 256; d <<= 1) {
            int u = (t >= d) ? tile[t - d] : 0;
            __syncthreads();
            tile[t] += u;
            __syncthreads();
        }
        if (p + t < hi) {
            int excl = base + tile[t] - v;
            offsets[p + t] = excl;
            cursor[p + t]  = excl;
            if (p + t == N - 1) offsets[N] = excl + v;
        }
        base += tile[255];
        __syncthreads();
    }
}

// ---------------------------------------------------------------------------
// Pass 3: reorder-LITE — edge ids only (4 B/edge scattered write). The rbf
// payload is NOT copied: gather reads rbf[e] directly (38 MB, L3-resident).
// ---------------------------------------------------------------------------
__global__ __launch_bounds__(256) void reorder_kernel(
    const int* __restrict__ idx, int* __restrict__ cursor,
    int* __restrict__ sorted, int E)
{
    int stride = gridDim.x * blockDim.x;
    for (int e = blockIdx.x * blockDim.x + threadIdx.x; e < E; e += stride) {
        int a = idx[e];
        int pos = atomicAdd(&cursor[a], 1);
        sorted[pos] = e;
    }
}

// ---------------------------------------------------------------------------
// Pass 4: fused gather + rbf projection + per-atom MLP (R3 structure).
// Block = 256 = 4 waves, 16 atoms/block. Each wave processes 2 atoms in
// PARALLEL (32-lane halves) x 2 sequential iterations. Half-wave lane hl owns
// features 4*hl..4*hl+3 (float4 m loads, 512 B/edge). Edge ids cached in
// registers (32-deep) and broadcast via shfl; batch-4 loads. rbf rows are
// loaded per-edge (uniform across the half-wave -> one line, L3-hit).
// Then swish -> LDS, layer1 with W1 transposed in LDS, shfl-reduce layer2.
// ---------------------------------------------------------------------------
__global__ __launch_bounds__(256) void gather_mlp_kernel(
    const float* __restrict__ m, const int* __restrict__ offsets,
    const int* __restrict__ sorted, const float* __restrict__ rbf,
    const float* __restrict__ W_rbf, const float* __restrict__ W1,
    const float* __restrict__ b1, const float* __restrict__ W2,
    const float* __restrict__ b2, float* __restrict__ out, int N)
{
    __shared__ float W1t[128][68];   // transposed W1, padded
    __shared__ float sb[4][4][132];  // [wave][atom][feat], padded

    const int t = threadIdx.x;
    const int lane = t & 63;
    const int w = t >> 6;
    const int h  = lane >> 5;   // half-wave: 0/1
    const int hl = lane & 31;   // lane within half

    // stage W1 transposed (vectorized): W1 is [64][128] row-major
    for (int k4 = t; k4 < 64 * 128 / 4; k4 += 256) {
        int k = k4 * 4;
        int j = k >> 7, f = k & 127;
        float4 v = *(const float4*)(W1 + k);
        W1t[f + 0][j] = v.x; W1t[f + 1][j] = v.y;
        W1t[f + 2][j] = v.z; W1t[f + 3][j] = v.w;
    }

    // per-lane W_rbf rows for features 4*hl..4*hl+3
    float wr[4][NR];
#pragma unroll
    for (int c = 0; c < 4; ++c)
#pragma unroll
        for (int r = 0; r < NR; ++r)
            wr[c][r] = W_rbf[(4 * hl + c) * NR + r];

    __syncthreads();

    const int nb = blockIdx.x * 16 + w * 4;

    for (int ta = 0; ta < 2; ++ta) {
        const int n = nb + ta * 2 + h;
        float a0 = 0.f, a1 = 0.f, a2 = 0.f, a3 = 0.f;
        int beg = 0, end = 0;
        if (n < N) { beg = offsets[n]; end = offsets[n + 1]; }

        // 32-deep register cache of this half's edge ids
        int eid = (beg + hl < end) ? sorted[beg + hl] : 0;

        for (int p0 = beg; p0 < end; p0 += 4) {
            int cnt = end - p0; if (cnt > 4) cnt = 4;
            int e4[4];
            float4 mv[4];
            float2 rv[4][3];
#pragma unroll
            for (int k = 0; k < 4; ++k) {
                int off = p0 - beg + k;
                int e;
                if (off < 32) e = __shfl(eid, (h << 5) + off);
                else e = (p0 + k < end) ? sorted[p0 + k] : __shfl(eid, h << 5);
                if (k >= cnt) e = __shfl(eid, h << 5);  // clamp to safe row
                e4[k] = e;
            }
#pragma unroll
            for (int k = 0; k < 4; ++k) {
                mv[k] = *(const float4*)(m + (long)e4[k] * NF + hl * 4);
                // rbf row of this edge: uniform address across the half-wave
                const float2* rp = (const float2*)(rbf + (long)e4[k] * NR);
                rv[k][0] = rp[0]; rv[k][1] = rp[1]; rv[k][2] = rp[2];
            }
#pragma unroll
            for (int k = 0; k < 4; ++k) {
                if (k < cnt) {
                    float f0 = rv[k][0].x * wr[0][0];
                    float f1 = rv[k][0].x * wr[1][0];
                    float f2 = rv[k][0].x * wr[2][0];
                    float f3 = rv[k][0].x * wr[3][0];
                    f0 = fmaf(rv[k][0].y, wr[0][1], f0);
                    f1 = fmaf(rv[k][0].y, wr[1][1], f1);
                    f2 = fmaf(rv[k][0].y, wr[2][1], f2);
                    f3 = fmaf(rv[k][0].y, wr[3][1], f3);
                    f0 = fmaf(rv[k][1].x, wr[0][2], f0);
                    f1 = fmaf(rv[k][1].x, wr[1][2], f1);
                    f2 = fmaf(rv[k][1].x, wr[2][2], f2);
                    f3 = fmaf(rv[k][1].x, wr[3][2], f3);
                    f0 = fmaf(rv[k][1].y, wr[0][3], f0);
                    f1 = fmaf(rv[k][1].y, wr[1][3], f1);
                    f2 = fmaf(rv[k][1].y, wr[2][3], f2);
                    f3 = fmaf(rv[k][1].y, wr[3][3], f3);
                    f0 = fmaf(rv[k][2].x, wr[0][4], f0);
                    f1 = fmaf(rv[k][2].x, wr[1][4], f1);
                    f2 = fmaf(rv[k][2].x, wr[2][4], f2);
                    f3 = fmaf(rv[k][2].x, wr[3][4], f3);
                    f0 = fmaf(rv[k][2].y, wr[0][5], f0);
                    f1 = fmaf(rv[k][2].y, wr[1][5], f1);
                    f2 = fmaf(rv[k][2].y, wr[2][5], f2);
                    f3 = fmaf(rv[k][2].y, wr[3][5], f3);
                    a0 = fmaf(mv[k].x, f0, a0);
                    a1 = fmaf(mv[k].y, f1, a1);
                    a2 = fmaf(mv[k].z, f2, a2);
                    a3 = fmaf(mv[k].w, f3, a3);
                }
            }
        }

        float s0 = a0 / (1.f + __expf(-a0));
        float s1 = a1 / (1.f + __expf(-a1));
        float s2 = a2 / (1.f + __expf(-a2));
        float s3 = a3 / (1.f + __expf(-a3));
        *(float4*)&sb[w][ta * 2 + h][4 * hl] = make_float4(s0, s1, s2, s3);
    }

    // layer 1: 16-lane group ag = atom (0..3 of this wave), lane lj owns
    // outputs 4*lj..4*lj+3   (sb[w] is wave-private: no block sync needed)
    const int ag = lane >> 4;
    const int lj = lane & 15;

    float4 bv = *(const float4*)(b1 + 4 * lj);
    float h0 = bv.x, h1 = bv.y, h2 = bv.z, h3 = bv.w;

    for (int f = 0; f < 128; f += 4) {
        float4 sv = *(const float4*)&sb[w][ag][f];
        float4 w0 = *(const float4*)&W1t[f + 0][4 * lj];
        float4 w1v = *(const float4*)&W1t[f + 1][4 * lj];
        float4 w2v = *(const float4*)&W1t[f + 2][4 * lj];
        float4 w3v = *(const float4*)&W1t[f + 3][4 * lj];
        h0 = fmaf(sv.x, w0.x, h0);  h1 = fmaf(sv.x, w0.y, h1);
        h2 = fmaf(sv.x, w0.z, h2);  h3 = fmaf(sv.x, w0.w, h3);
        h0 = fmaf(sv.y, w1v.x, h0); h1 = fmaf(sv.y, w1v.y, h1);
        h2 = fmaf(sv.y, w1v.z, h2); h3 = fmaf(sv.y, w1v.w, h3);
        h0 = fmaf(sv.z, w2v.x, h0); h1 = fmaf(sv.z, w2v.y, h1);
        h2 = fmaf(sv.z, w2v.z, h2); h3 = fmaf(sv.z, w2v.w, h3);
        h0 = fmaf(sv.w, w3v.x, h0); h1 = fmaf(sv.w, w3v.y, h1);
        h2 = fmaf(sv.w, w3v.z, h2); h3 = fmaf(sv.w, w3v.w, h3);
    }

    float4 w2 = *(const float4*)(W2 + 4 * lj);
    float r = (h0 / (1.f + __expf(-h0))) * w2.x
            + (h1 / (1.f + __expf(-h1))) * w2.y
            + (h2 / (1.f + __expf(-h2))) * w2.z
            + (h3 / (1.f + __expf(-h3))) * w2.w;

    r += __shfl_xor(r, 1);
    r += __shfl_xor(r, 2);
    r += __shfl_xor(r, 4);
    r += __shfl_xor(r, 8);

    int n = nb + ag;
    if (lj == 0 && n < N) out[n] = r + b2[0];
}

extern "C" void kernel_launch(void* const* d_in, const int* in_sizes, int n_in,
                              void* d_out, int out_size, void* d_ws, size_t ws_size,
                              hipStream_t stream) {
    const float* m     = (const float*)d_in[0];
    const float* rbf   = (const float*)d_in[1];
    const int*   idx   = (const int*)d_in[2];
    const float* W_rbf = (const float*)d_in[4];
    const float* W1    = (const float*)d_in[5];
    const float* b1    = (const float*)d_in[6];
    const float* W2    = (const float*)d_in[7];
    const float* b2    = (const float*)d_in[8];
    float* out = (float*)d_out;

    const int E = in_sizes[2];   // one atom index per edge
    const int N = out_size;      // out is [N, 1]

    // workspace layout (all segment starts 8B-aligned)
    int* count   = (int*)d_ws;                 // N
    int* offsets = count + N;                  // N+1
    int* cursor  = offsets + ((N + 2) & ~1);   // N
    int* sorted  = cursor + N;                 // E

    hipMemsetAsync(count, 0, (size_t)N * sizeof(int), stream);

    hist_kernel<<<2048, 256, 0, stream>>>(idx, count, E);
    scan_all_kernel<<<SCAN_BLOCKS, 256, 0, stream>>>(count, offsets, cursor, N);
    reorder_kernel<<<2048, 256, 0, stream>>>(idx, cursor, sorted, E);
    gather_mlp_kernel<<<(N + 15) / 16, 256, 0, stream>>>(
        m, offsets, sorted, rbf, W_rbf, W1, b1, W2, b2, out, N);
}